// Round 2
// 545.879 us; speedup vs baseline: 1.1377x; 1.1377x over previous
//
#include <hip/hip_runtime.h>

// ---------------------------------------------------------------------------
// SlidingWindowSelfAttention on MI355X (gfx950), bf16 MFMA pipeline:
//   cast(x,wqkv,wout) -> GEMM1 qkv (Q scaled, V written transposed)
//   -> flash attention (S^T = K Q^T formulation) -> GEMM2 out (fp32)
// R5b: same 256x256 / BK=64 / 4-phase counted-vmcnt GEMM as R5, but LDS is
//     STATIC 128 KiB (gfx950 LDS = 160 KiB) and kernel_launch contains only
//     kernel launches. R5's container failure was most plausibly launch
//     mechanics: hipFuncSetAttribute during graph capture (capture-poison,
//     Guideline 9) and/or >64KB *dynamic* LDS rejected when the ignored
//     attribute call failed. The schedule itself audits clean (uniform
//     barriers, consistent vmcnt ledger, in-bounds tail prefetch).
// R5 theory (unchanged): R4 counters (MfmaUtil 28.5, HBM 10%, VALU 16%)
//     showed the 2-barrier K-loop's implicit vmcnt(0) drain exposing full
//     HBM latency every BK=32 step. Fix = 8-phase-style schedule: counted
//     s_waitcnt vmcnt(8) (never 0 in loop) + setprio around MFMA clusters.
// ---------------------------------------------------------------------------

typedef __bf16 bf16x8 __attribute__((ext_vector_type(8)));
typedef float  f32x4  __attribute__((ext_vector_type(4)));
typedef unsigned short u16x4 __attribute__((ext_vector_type(4)));

#define MFMA(a, b, c) __builtin_amdgcn_mfma_f32_16x16x32_bf16(a, b, c, 0, 0, 0)

__device__ __forceinline__ unsigned short f2bf(float f) {
  union { float f; unsigned u; } v; v.f = f;
  unsigned r = v.u + 0x7FFFu + ((v.u >> 16) & 1u);   // RNE
  return (unsigned short)(r >> 16);
}

// async global->LDS, 16B/lane; LDS dest = wave-uniform base + lane*16
__device__ __forceinline__ void gl16(const void* g, void* l) {
  __builtin_amdgcn_global_load_lds(
      (const __attribute__((address_space(1))) unsigned int*)g,
      (__attribute__((address_space(3))) unsigned int*)l, 16, 0, 0);
}

// ---------------------------------------------------------------------------
__global__ void cast_bf16(const float4* __restrict__ in,
                          u16x4* __restrict__ out, int n4) {
  int i = blockIdx.x * blockDim.x + threadIdx.x;
  if (i < n4) {
    float4 v = in[i];
    u16x4 o;
    o[0] = f2bf(v.x); o[1] = f2bf(v.y); o[2] = f2bf(v.z); o[3] = f2bf(v.w);
    out[i] = o;
  }
}

// ---------------------------------------------------------------------------
// C = A * B^T. A:[M,K] bf16 row-major, B:[N,K] bf16 row-major (torch weight).
// 256x256 tile, BK=64, 8 waves each 128x64. Frag-major LDS (16 rows x 32 K
// per 1KB frag, lane-linear): conflict-free ds_read_b128 AND valid
// global_load_lds dest (wave-uniform base + lane*16).
// LDS ring: 2 buffers x 2 K-halves; per buffer: A frags (kk*16+m)*1024,
// B frags 32768+(kk*16+n)*1024. Buffer stride 65536, total 128 KiB STATIC.
// Schedule per K-tile g (buf p=g&1), phases (mh,kk):
//   ph1 (0,0): stage A(g+1,k1)   ph2 (1,0): stage B(g+1,k1), vmcnt(8)
//   ph3 (0,1): stage A(g+2,k0)   ph4 (1,1): stage B(g+2,k0), vmcnt(8)
// Each phase: stage ; 8x ds_read_b128 ; s_barrier ; lgkmcnt(0)+sched_barrier
//             ; setprio(1) 16x MFMA setprio(0) ; [vmcnt(8)] ; s_barrier.
// Region-safety: U(g,k0) readers done after ph2 trailing barrier (re-staged
// ph3); U(g,k1) after ph4 (re-staged next group's ph1). vmcnt(8) leaves the
// newest 4 half-tile stages in flight; everything older has landed before
// the barrier that precedes its consumers' ds_reads.
// MODE 1: qkv epilogue (Q scaled 1/sqrt(D), V transposed into VT[B,H,D,S]).
// MODE 2: fp32 row-major C.
template <int MODE>
__global__ __launch_bounds__(512, 2) void gemm_bt(
    const unsigned short* __restrict__ A, const unsigned short* __restrict__ Bw,
    void* __restrict__ C1, void* __restrict__ C2, int K, int Nstride) {
  __shared__ __align__(16) unsigned char sm[131072];  // static: 128 KiB of 160
  const int tid = threadIdx.x, lane = tid & 63, w = tid >> 6;   // 8 waves
  const int l15 = lane & 15, lg = lane >> 4;
  const int wr = w >> 2, wc = w & 3;          // wave tile: rows wr*128, cols wc*64

  // XCD-bijective swizzle (gridDim.x % 8 == 0 for both GEMMs), M=8192 fixed.
  int id = (int)blockIdx.x;
  int cpx = (int)gridDim.x >> 3;
  int sid = (id & 7) * cpx + (id >> 3);
  const int bm = (sid & 31) * 256;            // nmt = 8192/256 = 32
  const int bn = (sid >> 5) * 256;

  f32x4 acc[8][4] = {};
  const int nt = K >> 6;                      // K-tiles of 64

  // per-wave staging rows: wave w owns frags {w, w+8} of each operand
  const unsigned short* aRow0 = A  + (size_t)(bm + w * 16 + l15) * K + lg * 8;
  const unsigned short* aRow1 = A  + (size_t)(bm + (w + 8) * 16 + l15) * K + lg * 8;
  const unsigned short* bRow0 = Bw + (size_t)(bn + w * 16 + l15) * K + lg * 8;
  const unsigned short* bRow1 = Bw + (size_t)(bn + (w + 8) * 16 + l15) * K + lg * 8;

  auto stageA = [&](int t, int kk) {          // 16KB unit = 2 gl16 / wave
    int kt = ((t < nt) ? t : nt - 1) * 64 + kk * 32;  // clamp: dummy re-load at tail
    unsigned char* dst = sm + (t & 1) * 65536 + kk * 16384;
    gl16(aRow0 + kt, dst + w * 1024);
    gl16(aRow1 + kt, dst + (w + 8) * 1024);
  };
  auto stageB = [&](int t, int kk) {
    int kt = ((t < nt) ? t : nt - 1) * 64 + kk * 32;
    unsigned char* dst = sm + (t & 1) * 65536 + 32768 + kk * 16384;
    gl16(bRow0 + kt, dst + w * 1024);
    gl16(bRow1 + kt, dst + (w + 8) * 1024);
  };

  // prologue: tile0 full + tile1 k0 in flight (12 loads/wave)
  stageA(0, 0); stageB(0, 0);
  stageA(0, 1); stageB(0, 1);
  stageA(1, 0); stageB(1, 0);
  asm volatile("s_waitcnt vmcnt(8)" ::: "memory");  // U(0,k0) landed
  __builtin_amdgcn_s_barrier();

#define PHASE(mh, kk, STAGE_STMT, DO_VM)                                       \
  {                                                                            \
    STAGE_STMT;                                                                \
    bf16x8 af[4], bfr[4];                                                      \
    _Pragma("unroll") for (int i = 0; i < 4; i++)                              \
      af[i] = *(const bf16x8*)(cur + ((kk)*16 + wr * 8 + (mh)*4 + i) * 1024 +  \
                               lane * 16);                                     \
    _Pragma("unroll") for (int j = 0; j < 4; j++)                              \
      bfr[j] = *(const bf16x8*)(cur + 32768 + ((kk)*16 + wc * 4 + j) * 1024 +  \
                                lane * 16);                                    \
    __builtin_amdgcn_s_barrier();                                              \
    asm volatile("s_waitcnt lgkmcnt(0)" ::: "memory");                         \
    __builtin_amdgcn_sched_barrier(0);                                         \
    __builtin_amdgcn_s_setprio(1);                                             \
    _Pragma("unroll") for (int i = 0; i < 4; i++)                              \
      _Pragma("unroll") for (int j = 0; j < 4; j++)                            \
        acc[(mh)*4 + i][j] = MFMA(af[i], bfr[j], acc[(mh)*4 + i][j]);          \
    __builtin_amdgcn_s_setprio(0);                                             \
    __builtin_amdgcn_sched_barrier(0);                                         \
    if (DO_VM) asm volatile("s_waitcnt vmcnt(8)" ::: "memory");                \
    __builtin_amdgcn_s_barrier();                                              \
  }

  for (int g = 0; g < nt; ++g) {
    unsigned char* cur = sm + (g & 1) * 65536;
    PHASE(0, 0, stageA(g + 1, 1), false)
    PHASE(1, 0, stageB(g + 1, 1), true)
    PHASE(0, 1, stageA(g + 2, 0), false)
    PHASE(1, 1, stageB(g + 2, 0), true)
  }
#undef PHASE

  // drain in-flight LDS-DMA before exit: next block on this CU owns the LDS
  asm volatile("s_waitcnt vmcnt(0)" ::: "memory");

  // C/D layout: col n = lane&15, row m = (lane>>4)*4 + r  [m89/m91 verified]
  if (MODE == 1) {
    unsigned short* QK = (unsigned short*)C1;  // [8192][4096] = Q|K
    unsigned short* VT = (unsigned short*)C2;  // [2*16*128][4096]
    if (bn < 4096) {
      const float scl = (bn < 2048) ? 0.08838834764831845f : 1.0f;  // Q pre-scale
#pragma unroll
      for (int mi = 0; mi < 8; mi++) {
        int m0 = bm + wr * 128 + mi * 16 + lg * 4;
#pragma unroll
        for (int j = 0; j < 4; j++) {
          int n = bn + wc * 64 + j * 16 + l15;
#pragma unroll
          for (int r = 0; r < 4; r++)
            QK[(size_t)(m0 + r) * 4096 + n] = f2bf(acc[mi][j][r] * scl);
        }
      }
    } else {  // V: 4 consecutive m = consecutive s in VT -> packed 8B store
#pragma unroll
      for (int mi = 0; mi < 8; mi++) {
        int m0 = bm + wr * 128 + mi * 16 + lg * 4;
        int bb = m0 >> 12, s = m0 & 4095;
#pragma unroll
        for (int j = 0; j < 4; j++) {
          int n4 = bn + wc * 64 + j * 16 + l15 - 4096;
          int hh = n4 >> 7, d = n4 & 127;
          u16x4 pk;
#pragma unroll
          for (int r = 0; r < 4; r++) pk[r] = f2bf(acc[mi][j][r]);
          *(u16x4*)(VT + ((size_t)((bb * 16 + hh) * 128 + d) * 4096 + s)) = pk;
        }
      }
    }
  } else {
    float* C = (float*)C1;
#pragma unroll
    for (int mi = 0; mi < 8; mi++) {
      int m0 = bm + wr * 128 + mi * 16 + lg * 4;
#pragma unroll
      for (int j = 0; j < 4; j++) {
        int n = bn + wc * 64 + j * 16 + l15;
#pragma unroll
        for (int r = 0; r < 4; r++)
          C[(size_t)(m0 + r) * Nstride + n] = acc[mi][j][r];
      }
    }
  }
}

// ---------------------------------------------------------------------------
// Flash attention, S^T = K·Q^T formulation. Block = (b,h,128 queries),
// 4 waves x 32 queries. KV tiles of 64, span [q0-512, q0+128).
// C-layout col (lane&15) = query -> softmax reduces with 2 shuffles,
// P^T packs to ds_write_b64, O packs to 8B global stores.
__global__ __launch_bounds__(256, 2) void attn(
    const unsigned short* __restrict__ QK,  // [B*S][4096], Q pre-scaled
    const unsigned short* __restrict__ VT,  // [B*H*D][S]
    unsigned short* __restrict__ O) {       // [B*S][2048]
  __shared__ unsigned char sm[51200];
  // [0,16K): K frags [kvb4][ks4][lane]x16B   [16K,32K): V frags [db8][kvs2][lane]
  // [32K,50K): P^T per wave 4608B: [m 32][kv 64] bf16, row stride 144B
  const int tid = threadIdx.x, lane = tid & 63, w = tid >> 6;
  const int l15 = lane & 15, lg = lane >> 4;
  const int bid = blockIdx.x;
  const int qc = bid & 31, h = (bid >> 5) & 15, b = bid >> 9;
  const int q0 = qc * 128;

  // Q fragments (B-operand: lane&15 = query, lg*8 = d-chunk) direct to regs
  bf16x8 qf[2][4];
#pragma unroll
  for (int mb = 0; mb < 2; mb++) {
    const unsigned short* qrow =
        QK + (size_t)(b * 4096 + q0 + (2 * w + mb) * 16 + l15) * 4096 + h * 128 + lg * 8;
#pragma unroll
    for (int ks = 0; ks < 4; ks++) qf[mb][ks] = *(const bf16x8*)(qrow + ks * 32);
  }

  float mrun[2] = {-1e30f, -1e30f}, lrun[2] = {0.f, 0.f};
  f32x4 oacc[8][2] = {};  // O^T tiles [db][mb]: row=d, col=query

  const int t0 = (q0 < 512) ? (512 - q0) >> 6 : 0;  // skip kv<0 tiles
  unsigned char* Ps = sm + 32768 + w * 4608;

  for (int t = t0; t < 10; t++) {
    const int kv0 = q0 - 512 + t * 64;
    __syncthreads();
#pragma unroll
    for (int u = 0; u < 4; u++) {
      int f = w + u * 4;
      int kvb = f >> 2, ks = f & 3;
      gl16(QK + (size_t)(b * 4096 + kv0 + kvb * 16 + l15) * 4096 + 2048 + h * 128 + ks * 32 + lg * 8,
           sm + (kvb * 4 + ks) * 1024);
      int db = f >> 1, kvs = f & 1;
      gl16(VT + (size_t)((b * 16 + h) * 128 + db * 16 + l15) * 4096 + kv0 + kvs * 32 + lg * 8,
           sm + 16384 + (db * 2 + kvs) * 1024);
    }
    __syncthreads();

    // S^T tiles [kvb][mb]: D row = kv (lg*4+r), D col = query (l15)
    f32x4 sacc[4][2] = {};
#pragma unroll
    for (int ks = 0; ks < 4; ks++)
#pragma unroll
      for (int kvb = 0; kvb < 4; kvb++) {
        bf16x8 kf = *(const bf16x8*)(sm + (kvb * 4 + ks) * 1024 + lane * 16);
        sacc[kvb][0] = MFMA(kf, qf[0][ks], sacc[kvb][0]);
        sacc[kvb][1] = MFMA(kf, qf[1][ks], sacc[kvb][1]);
      }

    if (t <= 1 || t >= 8) {  // only window-edge / causal-edge tiles need masks
#pragma unroll
      for (int kvb = 0; kvb < 4; kvb++)
#pragma unroll
        for (int mb = 0; mb < 2; mb++) {
          int qg = q0 + w * 32 + mb * 16 + l15;
          int kgb = kv0 + kvb * 16 + lg * 4;
#pragma unroll
          for (int r = 0; r < 4; r++) {
            int diff = qg - (kgb + r);
            if (diff < 0 || diff > 512) sacc[kvb][mb][r] = -1e30f;
          }
        }
    }

#pragma unroll
    for (int mb = 0; mb < 2; mb++) {
      float tmax = -1e30f;
#pragma unroll
      for (int kvb = 0; kvb < 4; kvb++)
#pragma unroll
        for (int r = 0; r < 4; r++) tmax = fmaxf(tmax, sacc[kvb][mb][r]);
      tmax = fmaxf(tmax, __shfl_xor(tmax, 16));
      tmax = fmaxf(tmax, __shfl_xor(tmax, 32));
      float mnew = fmaxf(mrun[mb], tmax);
      float alpha = __expf(mrun[mb] - mnew);
      mrun[mb] = mnew;
      float lsum = 0.f;
#pragma unroll
      for (int kvb = 0; kvb < 4; kvb++) {
        u16x4 pk;
#pragma unroll
        for (int r = 0; r < 4; r++) {
          float p = __expf(sacc[kvb][mb][r] - mnew);
          lsum += p;
          pk[r] = f2bf(p);
        }
        *(u16x4*)(Ps + (mb * 16 + l15) * 144 + kvb * 32 + lg * 8) = pk;
      }
      lsum += __shfl_xor(lsum, 16);
      lsum += __shfl_xor(lsum, 32);
      lrun[mb] = lrun[mb] * alpha + lsum;
#pragma unroll
      for (int db = 0; db < 8; db++)
#pragma unroll
        for (int r = 0; r < 4; r++) oacc[db][mb][r] *= alpha;
    }

    // O^T += V^T · P^T  (A = V^T frag, lane-linear; B = P^T, contiguous b128)
#pragma unroll
    for (int kvs = 0; kvs < 2; kvs++) {
      bf16x8 pf0 = *(const bf16x8*)(Ps + (0 + l15) * 144 + kvs * 64 + lg * 16);
      bf16x8 pf1 = *(const bf16x8*)(Ps + (16 + l15) * 144 + kvs * 64 + lg * 16);
#pragma unroll
      for (int db = 0; db < 8; db++) {
        bf16x8 vf = *(const bf16x8*)(sm + 16384 + (db * 2 + kvs) * 1024 + lane * 16);
        oacc[db][0] = MFMA(vf, pf0, oacc[db][0]);
        oacc[db][1] = MFMA(vf, pf1, oacc[db][1]);
      }
    }
  }

#pragma unroll
  for (int mb = 0; mb < 2; mb++) {
    float inv = 1.0f / lrun[mb];
    int s = q0 + w * 32 + mb * 16 + l15;
    unsigned short* orow = O + (size_t)(b * 4096 + s) * 2048 + h * 128 + lg * 4;
#pragma unroll
    for (int db = 0; db < 8; db++) {
      u16x4 pk;
#pragma unroll
      for (int r = 0; r < 4; r++) pk[r] = f2bf(oacc[db][mb][r] * inv);
      *(u16x4*)(orow + db * 16) = pk;
    }
  }
}

// ---------------------------------------------------------------------------
extern "C" void kernel_launch(void* const* d_in, const int* in_sizes, int n_in,
                              void* d_out, int out_size, void* d_ws, size_t ws_size,
                              hipStream_t stream) {
  const float* x = (const float*)d_in[0];       // [2,4096,2048]
  const float* w_qkv = (const float*)d_in[1];   // [6144,2048]
  const float* w_out = (const float*)d_in[2];   // [2048,2048]
  float* out = (float*)d_out;                   // [2,4096,2048] fp32

  char* ws = (char*)d_ws;
  unsigned short* XB    = (unsigned short*)(ws);                         // 32M
  unsigned short* WQKVB = (unsigned short*)(ws + 33554432);              // 24M
  unsigned short* WOUTB = (unsigned short*)(ws + 58720256);              // 8M
  unsigned short* QKb   = (unsigned short*)(ws + 67108864);              // 64M
  unsigned short* VTb   = (unsigned short*)(ws + 134217728);             // 32M
  unsigned short* OB    = XB;  // XB dead after GEMM1; reuse for attention output
  // total workspace: 160 MiB

  cast_bf16<<<16384, 256, 0, stream>>>((const float4*)x, (u16x4*)XB, 4194304);
  cast_bf16<<<12288, 256, 0, stream>>>((const float4*)w_qkv, (u16x4*)WQKVB, 3145728);
  cast_bf16<<<4096, 256, 0, stream>>>((const float4*)w_out, (u16x4*)WOUTB, 1048576);

  // qkv = x @ w_qkv^T : M=8192, N=6144, K=2048 ; 256x256 tiles, 768 blocks
  gemm_bt<1><<<768, 512, 0, stream>>>(XB, WQKVB, QKb, VTb, 2048, 0);

  // sliding-window attention: grid = B*H*(S/128)
  attn<<<1024, 256, 0, stream>>>(QKb, VTb, OB);

  // out = o @ w_out^T : M=8192, N=2048, K=2048 ; 256x256 tiles, 256 blocks
  gemm_bt<2><<<256, 512, 0, stream>>>(OB, WOUTB, out, nullptr, 2048, 2048);
}

// Round 3
// 536.090 us; speedup vs baseline: 1.1584x; 1.0183x over previous
//
#include <hip/hip_runtime.h>

// ---------------------------------------------------------------------------
// SlidingWindowSelfAttention on MI355X (gfx950), bf16 MFMA pipeline:
//   cast(x,wqkv,wout) -> GEMM1 qkv (Q scaled, V written transposed)
//   -> flash attention (S^T = K Q^T formulation) -> GEMM2 out (fp32)
// R6: GEMM K-loop restructured to ONE barrier per phase. R5b counters
//     (MfmaUtil 36.6, phase time 1543cy vs 1030cy of work) showed the
//     2-barriers-per-phase lockstep serialized LDS reads against MFMA.
//     New phase: {stage | ds_read | [vmcnt(8)] | barrier | lgkm(0)+schedbar
//     | setprio(1) 16 MFMA setprio(0)} -- next phase's ds_reads issue
//     right after the MFMA cluster and overlap its execution.
//     Stage schedule shifted to ph2=(g+1,k1), ph4=(g+2,k0): every LDS
//     region rewrite is separated from its last reader's lgkmcnt(0) by an
//     intervening barrier (race-audited). B-frags read once per kk and
//     reused across the mh pair (24 instead of 32 ds_read_b128/tile).
//     attn: XCD-bijective grid swizzle (1024=8x128) so q-chunks sharing a
//     KV window stay on one XCD -> KV stages become L2 hits.
// ---------------------------------------------------------------------------

typedef __bf16 bf16x8 __attribute__((ext_vector_type(8)));
typedef float  f32x4  __attribute__((ext_vector_type(4)));
typedef unsigned short u16x4 __attribute__((ext_vector_type(4)));

#define MFMA(a, b, c) __builtin_amdgcn_mfma_f32_16x16x32_bf16(a, b, c, 0, 0, 0)

__device__ __forceinline__ unsigned short f2bf(float f) {
  union { float f; unsigned u; } v; v.f = f;
  unsigned r = v.u + 0x7FFFu + ((v.u >> 16) & 1u);   // RNE
  return (unsigned short)(r >> 16);
}

// async global->LDS, 16B/lane; LDS dest = wave-uniform base + lane*16
__device__ __forceinline__ void gl16(const void* g, void* l) {
  __builtin_amdgcn_global_load_lds(
      (const __attribute__((address_space(1))) unsigned int*)g,
      (__attribute__((address_space(3))) unsigned int*)l, 16, 0, 0);
}

// ---------------------------------------------------------------------------
__global__ void cast_bf16(const float4* __restrict__ in,
                          u16x4* __restrict__ out, int n4) {
  int i = blockIdx.x * blockDim.x + threadIdx.x;
  if (i < n4) {
    float4 v = in[i];
    u16x4 o;
    o[0] = f2bf(v.x); o[1] = f2bf(v.y); o[2] = f2bf(v.z); o[3] = f2bf(v.w);
    out[i] = o;
  }
}

// ---------------------------------------------------------------------------
// C = A * B^T. A:[M,K] bf16 row-major, B:[N,K] bf16 row-major (torch weight).
// 256x256 tile, BK=64, 8 waves each 128x64. Frag-major LDS (16 rows x 32 K
// per 1KB frag, lane-linear): conflict-free ds_read_b128 AND valid
// global_load_lds dest (wave-uniform base + lane*16).
// LDS ring: 2 buffers x 2 K-halves; per buffer: A frags (kk*16+m)*1024,
// B frags 32768+(kk*16+n)*1024. Buffer stride 65536, total 128 KiB STATIC.
// Phases per K-tile g (buf g&1), ONE barrier each:
//   ph1 (mh0,k0): reads A+B(k0)            ph2 (mh1,k0): stage(g+1,k1), vm(8)
//   ph3 (mh0,k1): reads A+B(k1)            ph4 (mh1,k1): stage(g+2,k0), vm(8)
// Write-safety (1 barrier/phase): region k1 of buf[(g+1)&1] last read in
// tile g-1 ph3/ph4, lgkm(0)-complete before ph1(g)'s barrier; staged in
// ph2(g) (after that barrier). Region k0 of buf[g&1] last read ph1/ph2(g),
// complete before ph3(g)'s barrier; staged in ph4(g). vmcnt(8) at ph2/ph4
// retires exactly the unit the next consumer phase needs, before a barrier.
// MODE 1: qkv epilogue (Q scaled 1/sqrt(D), V transposed into VT[B,H,D,S]).
// MODE 2: fp32 row-major C.
template <int MODE>
__global__ __launch_bounds__(512, 2) void gemm_bt(
    const unsigned short* __restrict__ A, const unsigned short* __restrict__ Bw,
    void* __restrict__ C1, void* __restrict__ C2, int K, int Nstride) {
  __shared__ __align__(16) unsigned char sm[131072];  // static: 128 KiB of 160
  const int tid = threadIdx.x, lane = tid & 63, w = tid >> 6;   // 8 waves
  const int l15 = lane & 15, lg = lane >> 4;
  const int wr = w >> 2, wc = w & 3;          // wave tile: rows wr*128, cols wc*64

  // XCD-bijective swizzle (gridDim.x % 8 == 0 for both GEMMs), M=8192 fixed.
  int id = (int)blockIdx.x;
  int cpx = (int)gridDim.x >> 3;
  int sid = (id & 7) * cpx + (id >> 3);
  const int bm = (sid & 31) * 256;            // nmt = 8192/256 = 32
  const int bn = (sid >> 5) * 256;

  f32x4 acc[8][4] = {};
  const int nt = K >> 6;                      // K-tiles of 64

  // per-wave staging rows: wave w owns frags {w, w+8} of each operand
  const unsigned short* aRow0 = A  + (size_t)(bm + w * 16 + l15) * K + lg * 8;
  const unsigned short* aRow1 = A  + (size_t)(bm + (w + 8) * 16 + l15) * K + lg * 8;
  const unsigned short* bRow0 = Bw + (size_t)(bn + w * 16 + l15) * K + lg * 8;
  const unsigned short* bRow1 = Bw + (size_t)(bn + (w + 8) * 16 + l15) * K + lg * 8;

  auto stageA = [&](int t, int kk) {          // 16KB unit = 2 gl16 / wave
    int kt = ((t < nt) ? t : nt - 1) * 64 + kk * 32;  // clamp: dummy re-load at tail
    unsigned char* dst = sm + (t & 1) * 65536 + kk * 16384;
    gl16(aRow0 + kt, dst + w * 1024);
    gl16(aRow1 + kt, dst + (w + 8) * 1024);
  };
  auto stageB = [&](int t, int kk) {
    int kt = ((t < nt) ? t : nt - 1) * 64 + kk * 32;
    unsigned char* dst = sm + (t & 1) * 65536 + 32768 + kk * 16384;
    gl16(bRow0 + kt, dst + w * 1024);
    gl16(bRow1 + kt, dst + (w + 8) * 1024);
  };

  // prologue: tile0 full + tile1 k0 in flight (12 loads/wave)
  stageA(0, 0); stageB(0, 0);
  stageA(0, 1); stageB(0, 1);
  stageA(1, 0); stageB(1, 0);
  asm volatile("s_waitcnt vmcnt(8)" ::: "memory");  // tile0.k0 landed
  __builtin_amdgcn_s_barrier();

  // One barrier per phase. READ_B: refresh bfr (ph1/ph3); else reuse (ph2/ph4).
#define PHASE(mh, kk, STAGE_STMT, DO_VM, READ_B)                               \
  {                                                                            \
    STAGE_STMT;                                                                \
    bf16x8 af[4];                                                              \
    _Pragma("unroll") for (int i = 0; i < 4; i++)                              \
      af[i] = *(const bf16x8*)(cur + ((kk)*16 + wr * 8 + (mh)*4 + i) * 1024 +  \
                               lane * 16);                                     \
    if (READ_B) {                                                              \
      _Pragma("unroll") for (int j = 0; j < 4; j++)                            \
        bfr[j] = *(const bf16x8*)(cur + 32768 +                                \
                                  ((kk)*16 + wc * 4 + j) * 1024 + lane * 16);  \
    }                                                                          \
    if (DO_VM) asm volatile("s_waitcnt vmcnt(8)" ::: "memory");                \
    __builtin_amdgcn_s_barrier();                                              \
    asm volatile("s_waitcnt lgkmcnt(0)" ::: "memory");                         \
    __builtin_amdgcn_sched_barrier(0);                                         \
    __builtin_amdgcn_s_setprio(1);                                             \
    _Pragma("unroll") for (int i = 0; i < 4; i++)                              \
      _Pragma("unroll") for (int j = 0; j < 4; j++)                            \
        acc[(mh)*4 + i][j] = MFMA(af[i], bfr[j], acc[(mh)*4 + i][j]);          \
    __builtin_amdgcn_s_setprio(0);                                             \
  }

  for (int g = 0; g < nt; ++g) {
    unsigned char* cur = sm + (g & 1) * 65536;
    bf16x8 bfr[4];
    PHASE(0, 0, , false, true)
    PHASE(1, 0, { stageA(g + 1, 1); stageB(g + 1, 1); }, true, false)
    PHASE(0, 1, , false, true)
    PHASE(1, 1, { stageA(g + 2, 0); stageB(g + 2, 0); }, true, false)
  }
#undef PHASE

  // drain in-flight LDS-DMA before exit: next block on this CU owns the LDS
  asm volatile("s_waitcnt vmcnt(0)" ::: "memory");

  // C/D layout: col n = lane&15, row m = (lane>>4)*4 + r  [m89/m91 verified]
  if (MODE == 1) {
    unsigned short* QK = (unsigned short*)C1;  // [8192][4096] = Q|K
    unsigned short* VT = (unsigned short*)C2;  // [2*16*128][4096]
    if (bn < 4096) {
      const float scl = (bn < 2048) ? 0.08838834764831845f : 1.0f;  // Q pre-scale
#pragma unroll
      for (int mi = 0; mi < 8; mi++) {
        int m0 = bm + wr * 128 + mi * 16 + lg * 4;
#pragma unroll
        for (int j = 0; j < 4; j++) {
          int n = bn + wc * 64 + j * 16 + l15;
#pragma unroll
          for (int r = 0; r < 4; r++)
            QK[(size_t)(m0 + r) * 4096 + n] = f2bf(acc[mi][j][r] * scl);
        }
      }
    } else {  // V: 4 consecutive m = consecutive s in VT -> packed 8B store
#pragma unroll
      for (int mi = 0; mi < 8; mi++) {
        int m0 = bm + wr * 128 + mi * 16 + lg * 4;
        int bb = m0 >> 12, s = m0 & 4095;
#pragma unroll
        for (int j = 0; j < 4; j++) {
          int n4 = bn + wc * 64 + j * 16 + l15 - 4096;
          int hh = n4 >> 7, d = n4 & 127;
          u16x4 pk;
#pragma unroll
          for (int r = 0; r < 4; r++) pk[r] = f2bf(acc[mi][j][r]);
          *(u16x4*)(VT + ((size_t)((bb * 16 + hh) * 128 + d) * 4096 + s)) = pk;
        }
      }
    }
  } else {
    float* C = (float*)C1;
#pragma unroll
    for (int mi = 0; mi < 8; mi++) {
      int m0 = bm + wr * 128 + mi * 16 + lg * 4;
#pragma unroll
      for (int j = 0; j < 4; j++) {
        int n = bn + wc * 64 + j * 16 + l15;
#pragma unroll
        for (int r = 0; r < 4; r++)
          C[(size_t)(m0 + r) * Nstride + n] = acc[mi][j][r];
      }
    }
  }
}

// ---------------------------------------------------------------------------
// Flash attention, S^T = K·Q^T formulation. Block = (b,h,128 queries),
// 4 waves x 32 queries. KV tiles of 64, span [q0-512, q0+128).
// C-layout col (lane&15) = query -> softmax reduces with 2 shuffles,
// P^T packs to ds_write_b64, O packs to 8B global stores.
// R6: XCD-bijective block swizzle (1024 = 8 x 128): consecutive q-chunks of
// one (b,h) stay on one XCD -> KV window stages hit that XCD's L2.
__global__ __launch_bounds__(256, 2) void attn(
    const unsigned short* __restrict__ QK,  // [B*S][4096], Q pre-scaled
    const unsigned short* __restrict__ VT,  // [B*H*D][S]
    unsigned short* __restrict__ O) {       // [B*S][2048]
  __shared__ unsigned char sm[51200];
  // [0,16K): K frags [kvb4][ks4][lane]x16B   [16K,32K): V frags [db8][kvs2][lane]
  // [32K,50K): P^T per wave 4608B: [m 32][kv 64] bf16, row stride 144B
  const int tid = threadIdx.x, lane = tid & 63, w = tid >> 6;
  const int l15 = lane & 15, lg = lane >> 4;
  const int bid = blockIdx.x;
  const int sid = (bid & 7) * 128 + (bid >> 3);   // XCD-contiguous q-chunks
  const int qc = sid & 31, h = (sid >> 5) & 15, b = sid >> 9;
  const int q0 = qc * 128;

  // Q fragments (B-operand: lane&15 = query, lg*8 = d-chunk) direct to regs
  bf16x8 qf[2][4];
#pragma unroll
  for (int mb = 0; mb < 2; mb++) {
    const unsigned short* qrow =
        QK + (size_t)(b * 4096 + q0 + (2 * w + mb) * 16 + l15) * 4096 + h * 128 + lg * 8;
#pragma unroll
    for (int ks = 0; ks < 4; ks++) qf[mb][ks] = *(const bf16x8*)(qrow + ks * 32);
  }

  float mrun[2] = {-1e30f, -1e30f}, lrun[2] = {0.f, 0.f};
  f32x4 oacc[8][2] = {};  // O^T tiles [db][mb]: row=d, col=query

  const int t0 = (q0 < 512) ? (512 - q0) >> 6 : 0;  // skip kv<0 tiles
  unsigned char* Ps = sm + 32768 + w * 4608;

  for (int t = t0; t < 10; t++) {
    const int kv0 = q0 - 512 + t * 64;
    __syncthreads();
#pragma unroll
    for (int u = 0; u < 4; u++) {
      int f = w + u * 4;
      int kvb = f >> 2, ks = f & 3;
      gl16(QK + (size_t)(b * 4096 + kv0 + kvb * 16 + l15) * 4096 + 2048 + h * 128 + ks * 32 + lg * 8,
           sm + (kvb * 4 + ks) * 1024);
      int db = f >> 1, kvs = f & 1;
      gl16(VT + (size_t)((b * 16 + h) * 128 + db * 16 + l15) * 4096 + kv0 + kvs * 32 + lg * 8,
           sm + 16384 + (db * 2 + kvs) * 1024);
    }
    __syncthreads();

    // S^T tiles [kvb][mb]: D row = kv (lg*4+r), D col = query (l15)
    f32x4 sacc[4][2] = {};
#pragma unroll
    for (int ks = 0; ks < 4; ks++)
#pragma unroll
      for (int kvb = 0; kvb < 4; kvb++) {
        bf16x8 kf = *(const bf16x8*)(sm + (kvb * 4 + ks) * 1024 + lane * 16);
        sacc[kvb][0] = MFMA(kf, qf[0][ks], sacc[kvb][0]);
        sacc[kvb][1] = MFMA(kf, qf[1][ks], sacc[kvb][1]);
      }

    if (t <= 1 || t >= 8) {  // only window-edge / causal-edge tiles need masks
#pragma unroll
      for (int kvb = 0; kvb < 4; kvb++)
#pragma unroll
        for (int mb = 0; mb < 2; mb++) {
          int qg = q0 + w * 32 + mb * 16 + l15;
          int kgb = kv0 + kvb * 16 + lg * 4;
#pragma unroll
          for (int r = 0; r < 4; r++) {
            int diff = qg - (kgb + r);
            if (diff < 0 || diff > 512) sacc[kvb][mb][r] = -1e30f;
          }
        }
    }

#pragma unroll
    for (int mb = 0; mb < 2; mb++) {
      float tmax = -1e30f;
#pragma unroll
      for (int kvb = 0; kvb < 4; kvb++)
#pragma unroll
        for (int r = 0; r < 4; r++) tmax = fmaxf(tmax, sacc[kvb][mb][r]);
      tmax = fmaxf(tmax, __shfl_xor(tmax, 16));
      tmax = fmaxf(tmax, __shfl_xor(tmax, 32));
      float mnew = fmaxf(mrun[mb], tmax);
      float alpha = __expf(mrun[mb] - mnew);
      mrun[mb] = mnew;
      float lsum = 0.f;
#pragma unroll
      for (int kvb = 0; kvb < 4; kvb++) {
        u16x4 pk;
#pragma unroll
        for (int r = 0; r < 4; r++) {
          float p = __expf(sacc[kvb][mb][r] - mnew);
          lsum += p;
          pk[r] = f2bf(p);
        }
        *(u16x4*)(Ps + (mb * 16 + l15) * 144 + kvb * 32 + lg * 8) = pk;
      }
      lsum += __shfl_xor(lsum, 16);
      lsum += __shfl_xor(lsum, 32);
      lrun[mb] = lrun[mb] * alpha + lsum;
#pragma unroll
      for (int db = 0; db < 8; db++)
#pragma unroll
        for (int r = 0; r < 4; r++) oacc[db][mb][r] *= alpha;
    }

    // O^T += V^T · P^T  (A = V^T frag, lane-linear; B = P^T, contiguous b128)
#pragma unroll
    for (int kvs = 0; kvs < 2; kvs++) {
      bf16x8 pf0 = *(const bf16x8*)(Ps + (0 + l15) * 144 + kvs * 64 + lg * 16);
      bf16x8 pf1 = *(const bf16x8*)(Ps + (16 + l15) * 144 + kvs * 64 + lg * 16);
#pragma unroll
      for (int db = 0; db < 8; db++) {
        bf16x8 vf = *(const bf16x8*)(sm + 16384 + (db * 2 + kvs) * 1024 + lane * 16);
        oacc[db][0] = MFMA(vf, pf0, oacc[db][0]);
        oacc[db][1] = MFMA(vf, pf1, oacc[db][1]);
      }
    }
  }

#pragma unroll
  for (int mb = 0; mb < 2; mb++) {
    float inv = 1.0f / lrun[mb];
    int s = q0 + w * 32 + mb * 16 + l15;
    unsigned short* orow = O + (size_t)(b * 4096 + s) * 2048 + h * 128 + lg * 4;
#pragma unroll
    for (int db = 0; db < 8; db++) {
      u16x4 pk;
#pragma unroll
      for (int r = 0; r < 4; r++) pk[r] = f2bf(oacc[db][mb][r] * inv);
      *(u16x4*)(orow + db * 16) = pk;
    }
  }
}

// ---------------------------------------------------------------------------
extern "C" void kernel_launch(void* const* d_in, const int* in_sizes, int n_in,
                              void* d_out, int out_size, void* d_ws, size_t ws_size,
                              hipStream_t stream) {
  const float* x = (const float*)d_in[0];       // [2,4096,2048]
  const float* w_qkv = (const float*)d_in[1];   // [6144,2048]
  const float* w_out = (const float*)d_in[2];   // [2048,2048]
  float* out = (float*)d_out;                   // [2,4096,2048] fp32

  char* ws = (char*)d_ws;
  unsigned short* XB    = (unsigned short*)(ws);                         // 32M
  unsigned short* WQKVB = (unsigned short*)(ws + 33554432);              // 24M
  unsigned short* WOUTB = (unsigned short*)(ws + 58720256);              // 8M
  unsigned short* QKb   = (unsigned short*)(ws + 67108864);              // 64M
  unsigned short* VTb   = (unsigned short*)(ws + 134217728);             // 32M
  unsigned short* OB    = XB;  // XB dead after GEMM1; reuse for attention output
  // total workspace: 160 MiB

  cast_bf16<<<16384, 256, 0, stream>>>((const float4*)x, (u16x4*)XB, 4194304);
  cast_bf16<<<12288, 256, 0, stream>>>((const float4*)w_qkv, (u16x4*)WQKVB, 3145728);
  cast_bf16<<<4096, 256, 0, stream>>>((const float4*)w_out, (u16x4*)WOUTB, 1048576);

  // qkv = x @ w_qkv^T : M=8192, N=6144, K=2048 ; 256x256 tiles, 768 blocks
  gemm_bt<1><<<768, 512, 0, stream>>>(XB, WQKVB, QKb, VTb, 2048, 0);

  // sliding-window attention: grid = B*H*(S/128)
  attn<<<1024, 256, 0, stream>>>(QKb, VTb, OB);

  // out = o @ w_out^T : M=8192, N=2048, K=2048 ; 256x256 tiles, 256 blocks
  gemm_bt<2><<<256, 512, 0, stream>>>(OB, WOUTB, out, nullptr, 2048, 2048);
}

// Round 4
// 527.712 us; speedup vs baseline: 1.1768x; 1.0159x over previous
//
#include <hip/hip_runtime.h>

// ---------------------------------------------------------------------------
// SlidingWindowSelfAttention on MI355X (gfx950), bf16 MFMA pipeline:
//   cast(x,wqkv,wout) -> GEMM1 qkv (Q scaled, V written transposed)
//   -> flash attention (S^T = K Q^T formulation) -> GEMM2 out (fp32)
// R7: GEMM = 256x256, BK=32, LDS as FOUR independent 32KB K-slices, staged
//     3 deep (12 gl16/wave outstanding, ~3 K-tiles of lead). Theory: R6's
//     barrier-halving null + 6065cy/K-tile vs 2400cy MFMA content shows the
//     binding constraint is the global->LDS service rate (~7.4TB/s wall seen
//     at R4's 7.5TB/s); deep backlog keeps the service pipe saturated and
//     removes latency exposure entirely. vmcnt(8) once per K-tile retires
//     exactly the next tile's slice, always before a barrier.
//     attn = K double-buffered (stage K(t+1) at tile top), V re-staged in
//     place after a post-PV barrier; two counted vmcnt(4) replace the full
//     per-tile vmcnt(0) drain. LDS 66KB -> still 2 blocks/CU.
// ---------------------------------------------------------------------------

typedef __bf16 bf16x8 __attribute__((ext_vector_type(8)));
typedef float  f32x4  __attribute__((ext_vector_type(4)));
typedef unsigned short u16x4 __attribute__((ext_vector_type(4)));

#define MFMA(a, b, c) __builtin_amdgcn_mfma_f32_16x16x32_bf16(a, b, c, 0, 0, 0)

__device__ __forceinline__ unsigned short f2bf(float f) {
  union { float f; unsigned u; } v; v.f = f;
  unsigned r = v.u + 0x7FFFu + ((v.u >> 16) & 1u);   // RNE
  return (unsigned short)(r >> 16);
}

// async global->LDS, 16B/lane; LDS dest = wave-uniform base + lane*16
__device__ __forceinline__ void gl16(const void* g, void* l) {
  __builtin_amdgcn_global_load_lds(
      (const __attribute__((address_space(1))) unsigned int*)g,
      (__attribute__((address_space(3))) unsigned int*)l, 16, 0, 0);
}

// ---------------------------------------------------------------------------
__global__ void cast_bf16(const float4* __restrict__ in,
                          u16x4* __restrict__ out, int n4) {
  int i = blockIdx.x * blockDim.x + threadIdx.x;
  if (i < n4) {
    float4 v = in[i];
    u16x4 o;
    o[0] = f2bf(v.x); o[1] = f2bf(v.y); o[2] = f2bf(v.z); o[3] = f2bf(v.w);
    out[i] = o;
  }
}

// ---------------------------------------------------------------------------
// C = A * B^T. A:[M,K] bf16 row-major, B:[N,K] bf16 row-major (torch weight).
// 256x256 tile, BK=32, 8 waves each 128x64. Frag-major LDS (16 rows x 32 K
// per 1KB frag, lane-linear): conflict-free ds_read_b128 AND valid
// global_load_lds dest (wave-uniform base + lane*16).
// LDS = 4 slices x 32KB (A frags 16x1KB | B frags 16x1KB). Slice for tile g
// = sm + (g&3)*32768. Stage(g+3) issued in ph2(g): its region (slice
// (g-1)&3) was last read in tile g-1, whose lgkmcnt(0) all waves passed
// before ph1(g)'s barrier -> safe. vmcnt(8) in ph2(g) retires tile g+1's
// 4-load unit (FIFO: g+1,g+2,g+3 outstanding = 12 -> wait to 8), before
// ph2's barrier so it is visible to all waves' ph1(g+1) reads.
// Phases per K-tile g, ONE barrier each:
//   ph1: read A(mh0)+B  | bar | lgkm | 16 MFMA acc[0..3][*]
//   ph2: read A(mh1), stage(g+3), vmcnt(8) | bar | lgkm | 16 MFMA acc[4..7][*]
// MODE 1: qkv epilogue (Q scaled 1/sqrt(D), V transposed into VT[B,H,D,S]).
// MODE 2: fp32 row-major C.
template <int MODE>
__global__ __launch_bounds__(512, 2) void gemm_bt(
    const unsigned short* __restrict__ A, const unsigned short* __restrict__ Bw,
    void* __restrict__ C1, void* __restrict__ C2, int K, int Nstride) {
  __shared__ __align__(16) unsigned char sm[131072];  // 4 x 32KB slices
  const int tid = threadIdx.x, lane = tid & 63, w = tid >> 6;   // 8 waves
  const int l15 = lane & 15, lg = lane >> 4;
  const int wr = w >> 2, wc = w & 3;          // wave tile: rows wr*128, cols wc*64

  // XCD-bijective swizzle (gridDim.x % 8 == 0 for both GEMMs), M=8192 fixed.
  int id = (int)blockIdx.x;
  int cpx = (int)gridDim.x >> 3;
  int sid = (id & 7) * cpx + (id >> 3);
  const int bm = (sid & 31) * 256;            // nmt = 8192/256 = 32
  const int bn = (sid >> 5) * 256;

  f32x4 acc[8][4] = {};
  const int nt = K >> 5;                      // K-tiles of 32

  // per-wave staging rows: wave w owns frags {w, w+8} of each operand
  const unsigned short* aRow0 = A  + (size_t)(bm + w * 16 + l15) * K + lg * 8;
  const unsigned short* aRow1 = A  + (size_t)(bm + (w + 8) * 16 + l15) * K + lg * 8;
  const unsigned short* bRow0 = Bw + (size_t)(bn + w * 16 + l15) * K + lg * 8;
  const unsigned short* bRow1 = Bw + (size_t)(bn + (w + 8) * 16 + l15) * K + lg * 8;

  auto stage = [&](int t) {                   // one 32KB slice = 4 gl16/wave
    int kt = ((t < nt) ? t : nt - 1) * 32;    // clamp: dummy re-load at tail
    unsigned char* dst = sm + (t & 3) * 32768;
    gl16(aRow0 + kt, dst + w * 1024);
    gl16(aRow1 + kt, dst + (w + 8) * 1024);
    gl16(bRow0 + kt, dst + 16384 + w * 1024);
    gl16(bRow1 + kt, dst + 16384 + (w + 8) * 1024);
  };

  // prologue: slices 0,1,2 in flight (12 loads/wave)
  stage(0); stage(1); stage(2);
  asm volatile("s_waitcnt vmcnt(8)" ::: "memory");  // slice 0 landed
  __builtin_amdgcn_s_barrier();

  for (int g = 0; g < nt; ++g) {
    unsigned char* cur = sm + (g & 3) * 32768;
    bf16x8 af[4], bfr[4];
    // ---- ph1: A(mh0) + B reads, MFMA quadrant 0 ----
#pragma unroll
    for (int i = 0; i < 4; i++)
      af[i] = *(const bf16x8*)(cur + (wr * 8 + i) * 1024 + lane * 16);
#pragma unroll
    for (int j = 0; j < 4; j++)
      bfr[j] = *(const bf16x8*)(cur + 16384 + (wc * 4 + j) * 1024 + lane * 16);
    __builtin_amdgcn_s_barrier();
    asm volatile("s_waitcnt lgkmcnt(0)" ::: "memory");
    __builtin_amdgcn_sched_barrier(0);
    __builtin_amdgcn_s_setprio(1);
#pragma unroll
    for (int i = 0; i < 4; i++)
#pragma unroll
      for (int j = 0; j < 4; j++)
        acc[i][j] = MFMA(af[i], bfr[j], acc[i][j]);
    __builtin_amdgcn_s_setprio(0);
    // ---- ph2: A(mh1) reads (B reused), stage(g+3), MFMA quadrant 1 ----
#pragma unroll
    for (int i = 0; i < 4; i++)
      af[i] = *(const bf16x8*)(cur + (wr * 8 + 4 + i) * 1024 + lane * 16);
    stage(g + 3);
    asm volatile("s_waitcnt vmcnt(8)" ::: "memory");  // tile g+1 slice landed
    __builtin_amdgcn_s_barrier();
    asm volatile("s_waitcnt lgkmcnt(0)" ::: "memory");
    __builtin_amdgcn_sched_barrier(0);
    __builtin_amdgcn_s_setprio(1);
#pragma unroll
    for (int i = 0; i < 4; i++)
#pragma unroll
      for (int j = 0; j < 4; j++)
        acc[4 + i][j] = MFMA(af[i], bfr[j], acc[4 + i][j]);
    __builtin_amdgcn_s_setprio(0);
  }

  // drain in-flight LDS-DMA before exit: next block on this CU owns the LDS
  asm volatile("s_waitcnt vmcnt(0)" ::: "memory");

  // C/D layout: col n = lane&15, row m = (lane>>4)*4 + r  [m89/m91 verified]
  if (MODE == 1) {
    unsigned short* QK = (unsigned short*)C1;  // [8192][4096] = Q|K
    unsigned short* VT = (unsigned short*)C2;  // [2*16*128][4096]
    if (bn < 4096) {
      const float scl = (bn < 2048) ? 0.08838834764831845f : 1.0f;  // Q pre-scale
#pragma unroll
      for (int mi = 0; mi < 8; mi++) {
        int m0 = bm + wr * 128 + mi * 16 + lg * 4;
#pragma unroll
        for (int j = 0; j < 4; j++) {
          int n = bn + wc * 64 + j * 16 + l15;
#pragma unroll
          for (int r = 0; r < 4; r++)
            QK[(size_t)(m0 + r) * 4096 + n] = f2bf(acc[mi][j][r] * scl);
        }
      }
    } else {  // V: 4 consecutive m = consecutive s in VT -> packed 8B store
#pragma unroll
      for (int mi = 0; mi < 8; mi++) {
        int m0 = bm + wr * 128 + mi * 16 + lg * 4;
        int bb = m0 >> 12, s = m0 & 4095;
#pragma unroll
        for (int j = 0; j < 4; j++) {
          int n4 = bn + wc * 64 + j * 16 + l15 - 4096;
          int hh = n4 >> 7, d = n4 & 127;
          u16x4 pk;
#pragma unroll
          for (int r = 0; r < 4; r++) pk[r] = f2bf(acc[mi][j][r]);
          *(u16x4*)(VT + ((size_t)((bb * 16 + hh) * 128 + d) * 4096 + s)) = pk;
        }
      }
    }
  } else {
    float* C = (float*)C1;
#pragma unroll
    for (int mi = 0; mi < 8; mi++) {
      int m0 = bm + wr * 128 + mi * 16 + lg * 4;
#pragma unroll
      for (int j = 0; j < 4; j++) {
        int n = bn + wc * 64 + j * 16 + l15;
#pragma unroll
        for (int r = 0; r < 4; r++)
          C[(size_t)(m0 + r) * Nstride + n] = acc[mi][j][r];
      }
    }
  }
}

// ---------------------------------------------------------------------------
// Flash attention, S^T = K·Q^T formulation. Block = (b,h,128 queries),
// 4 waves x 32 queries. KV tiles of 64, span [q0-512, q0+128).
// R7 pipeline: K double-buffered (Kbuf[2] 16KB each), V single-buffered,
// staged late. Per tile t (X=t&1):
//   stage K(t+1)->Kbuf[X^1] | S-MFMA reads Kbuf[X] | mask/softmax/P-writes
//   vmcnt(4)+bar  [retires V(t); K(t+1) remains in flight]
//   PV reads Ps+V | bar [PV reads done] | stage V(t+1)->V
//   vmcnt(4)+bar  [retires K(t+1); V(t+1) remains in flight]
// P^T is per-wave (stride 144, 2-way bank alias only); same-wave ds order
// makes P write->read safe without barriers. LDS 66KB -> 2 blocks/CU.
__global__ __launch_bounds__(256, 2) void attn(
    const unsigned short* __restrict__ QK,  // [B*S][4096], Q pre-scaled
    const unsigned short* __restrict__ VT,  // [B*H*D][S]
    unsigned short* __restrict__ O) {       // [B*S][2048]
  __shared__ unsigned char sm[67584];
  // [0,16K): Kbuf0  [16K,32K): Kbuf1  [32K,48K): V frags [db8][kvs2][lane]
  // [48K,66K): P^T per wave 4608B: [m 32][kv 64] bf16, row stride 144B
  const int tid = threadIdx.x, lane = tid & 63, w = tid >> 6;
  const int l15 = lane & 15, lg = lane >> 4;
  const int bid = blockIdx.x;
  const int sid = (bid & 7) * 128 + (bid >> 3);   // XCD-contiguous q-chunks
  const int qc = sid & 31, h = (sid >> 5) & 15, b = sid >> 9;
  const int q0 = qc * 128;

  // Q fragments (B-operand: lane&15 = query, lg*8 = d-chunk) direct to regs
  bf16x8 qf[2][4];
#pragma unroll
  for (int mb = 0; mb < 2; mb++) {
    const unsigned short* qrow =
        QK + (size_t)(b * 4096 + q0 + (2 * w + mb) * 16 + l15) * 4096 + h * 128 + lg * 8;
#pragma unroll
    for (int ks = 0; ks < 4; ks++) qf[mb][ks] = *(const bf16x8*)(qrow + ks * 32);
  }

  float mrun[2] = {-1e30f, -1e30f}, lrun[2] = {0.f, 0.f};
  f32x4 oacc[8][2] = {};  // O^T tiles [db][mb]: row=d, col=query

  const int t0 = (q0 < 512) ? (512 - q0) >> 6 : 0;  // skip kv<0 tiles
  unsigned char* Ps = sm + 49152 + w * 4608;

  // prologue: stage K(t0)->Kbuf[t0&1] and V(t0)->V, full drain once
  {
    const int kv0 = q0 - 512 + t0 * 64;
#pragma unroll
    for (int u = 0; u < 4; u++) {
      int f = w + u * 4;
      int kvb = f >> 2, ks = f & 3;
      gl16(QK + (size_t)(b * 4096 + kv0 + kvb * 16 + l15) * 4096 + 2048 + h * 128 + ks * 32 + lg * 8,
           sm + (t0 & 1) * 16384 + f * 1024);
      int db = f >> 1, kvs = f & 1;
      gl16(VT + (size_t)((b * 16 + h) * 128 + db * 16 + l15) * 4096 + kv0 + kvs * 32 + lg * 8,
           sm + 32768 + f * 1024);
    }
  }
  asm volatile("s_waitcnt vmcnt(0)" ::: "memory");
  __builtin_amdgcn_s_barrier();

  for (int t = t0; t < 10; t++) {
    const int kv0 = q0 - 512 + t * 64;
    const int X = t & 1;
    const int tn = (t + 1 < 10) ? t + 1 : 9;        // clamp: dummy tail stage
    const int kvn = q0 - 512 + tn * 64;

    // stage K(t+1) -> Kbuf[X^1] (region's last readers synced 2 bars ago)
#pragma unroll
    for (int u = 0; u < 4; u++) {
      int f = w + u * 4;
      int kvb = f >> 2, ks = f & 3;
      gl16(QK + (size_t)(b * 4096 + kvn + kvb * 16 + l15) * 4096 + 2048 + h * 128 + ks * 32 + lg * 8,
           sm + (X ^ 1) * 16384 + f * 1024);
    }

    // S^T tiles [kvb][mb]: D row = kv (lg*4+r), D col = query (l15)
    f32x4 sacc[4][2] = {};
#pragma unroll
    for (int ks = 0; ks < 4; ks++)
#pragma unroll
      for (int kvb = 0; kvb < 4; kvb++) {
        bf16x8 kf = *(const bf16x8*)(sm + X * 16384 + (kvb * 4 + ks) * 1024 + lane * 16);
        sacc[kvb][0] = MFMA(kf, qf[0][ks], sacc[kvb][0]);
        sacc[kvb][1] = MFMA(kf, qf[1][ks], sacc[kvb][1]);
      }

    if (t <= 1 || t >= 8) {  // only window-edge / causal-edge tiles need masks
#pragma unroll
      for (int kvb = 0; kvb < 4; kvb++)
#pragma unroll
        for (int mb = 0; mb < 2; mb++) {
          int qg = q0 + w * 32 + mb * 16 + l15;
          int kgb = kv0 + kvb * 16 + lg * 4;
#pragma unroll
          for (int r = 0; r < 4; r++) {
            int diff = qg - (kgb + r);
            if (diff < 0 || diff > 512) sacc[kvb][mb][r] = -1e30f;
          }
        }
    }

#pragma unroll
    for (int mb = 0; mb < 2; mb++) {
      float tmax = -1e30f;
#pragma unroll
      for (int kvb = 0; kvb < 4; kvb++)
#pragma unroll
        for (int r = 0; r < 4; r++) tmax = fmaxf(tmax, sacc[kvb][mb][r]);
      tmax = fmaxf(tmax, __shfl_xor(tmax, 16));
      tmax = fmaxf(tmax, __shfl_xor(tmax, 32));
      float mnew = fmaxf(mrun[mb], tmax);
      float alpha = __expf(mrun[mb] - mnew);
      mrun[mb] = mnew;
      float lsum = 0.f;
#pragma unroll
      for (int kvb = 0; kvb < 4; kvb++) {
        u16x4 pk;
#pragma unroll
        for (int r = 0; r < 4; r++) {
          float p = __expf(sacc[kvb][mb][r] - mnew);
          lsum += p;
          pk[r] = f2bf(p);
        }
        *(u16x4*)(Ps + (mb * 16 + l15) * 144 + kvb * 32 + lg * 8) = pk;
      }
      lsum += __shfl_xor(lsum, 16);
      lsum += __shfl_xor(lsum, 32);
      lrun[mb] = lrun[mb] * alpha + lsum;
#pragma unroll
      for (int db = 0; db < 8; db++)
#pragma unroll
        for (int r = 0; r < 4; r++) oacc[db][mb][r] *= alpha;
    }

    // V(t) landed (FIFO: V(t) older than K(t+1); 8 -> 4 outstanding)
    asm volatile("s_waitcnt vmcnt(4)" ::: "memory");
    __builtin_amdgcn_s_barrier();

    // O^T += V^T · P^T  (A = V^T frag, lane-linear; B = P^T, contiguous b128)
#pragma unroll
    for (int kvs = 0; kvs < 2; kvs++) {
      bf16x8 pf0 = *(const bf16x8*)(Ps + (0 + l15) * 144 + kvs * 64 + lg * 16);
      bf16x8 pf1 = *(const bf16x8*)(Ps + (16 + l15) * 144 + kvs * 64 + lg * 16);
#pragma unroll
      for (int db = 0; db < 8; db++) {
        bf16x8 vf = *(const bf16x8*)(sm + 32768 + (db * 2 + kvs) * 1024 + lane * 16);
        oacc[db][0] = MFMA(vf, pf0, oacc[db][0]);
        oacc[db][1] = MFMA(vf, pf1, oacc[db][1]);
      }
    }
    __builtin_amdgcn_s_barrier();   // all PV reads of V done block-wide

    // stage V(t+1) -> V region
#pragma unroll
    for (int u = 0; u < 4; u++) {
      int f = w + u * 4;
      int db = f >> 1, kvs = f & 1;
      gl16(VT + (size_t)((b * 16 + h) * 128 + db * 16 + l15) * 4096 + kvn + kvs * 32 + lg * 8,
           sm + 32768 + f * 1024);
    }
    // K(t+1) landed (FIFO: K(t+1) older than V(t+1); 8 -> 4 outstanding)
    asm volatile("s_waitcnt vmcnt(4)" ::: "memory");
    __builtin_amdgcn_s_barrier();
  }

  // drain dummy tail stages before exit (next block owns this LDS)
  asm volatile("s_waitcnt vmcnt(0)" ::: "memory");

#pragma unroll
  for (int mb = 0; mb < 2; mb++) {
    float inv = 1.0f / lrun[mb];
    int s = q0 + w * 32 + mb * 16 + l15;
    unsigned short* orow = O + (size_t)(b * 4096 + s) * 2048 + h * 128 + lg * 4;
#pragma unroll
    for (int db = 0; db < 8; db++) {
      u16x4 pk;
#pragma unroll
      for (int r = 0; r < 4; r++) pk[r] = f2bf(oacc[db][mb][r] * inv);
      *(u16x4*)(orow + db * 16) = pk;
    }
  }
}

// ---------------------------------------------------------------------------
extern "C" void kernel_launch(void* const* d_in, const int* in_sizes, int n_in,
                              void* d_out, int out_size, void* d_ws, size_t ws_size,
                              hipStream_t stream) {
  const float* x = (const float*)d_in[0];       // [2,4096,2048]
  const float* w_qkv = (const float*)d_in[1];   // [6144,2048]
  const float* w_out = (const float*)d_in[2];   // [2048,2048]
  float* out = (float*)d_out;                   // [2,4096,2048] fp32

  char* ws = (char*)d_ws;
  unsigned short* XB    = (unsigned short*)(ws);                         // 32M
  unsigned short* WQKVB = (unsigned short*)(ws + 33554432);              // 24M
  unsigned short* WOUTB = (unsigned short*)(ws + 58720256);              // 8M
  unsigned short* QKb   = (unsigned short*)(ws + 67108864);              // 64M
  unsigned short* VTb   = (unsigned short*)(ws + 134217728);             // 32M
  unsigned short* OB    = XB;  // XB dead after GEMM1; reuse for attention output
  // total workspace: 160 MiB

  cast_bf16<<<16384, 256, 0, stream>>>((const float4*)x, (u16x4*)XB, 4194304);
  cast_bf16<<<12288, 256, 0, stream>>>((const float4*)w_qkv, (u16x4*)WQKVB, 3145728);
  cast_bf16<<<4096, 256, 0, stream>>>((const float4*)w_out, (u16x4*)WOUTB, 1048576);

  // qkv = x @ w_qkv^T : M=8192, N=6144, K=2048 ; 256x256 tiles, 768 blocks
  gemm_bt<1><<<768, 512, 0, stream>>>(XB, WQKVB, QKb, VTb, 2048, 0);

  // sliding-window attention: grid = B*H*(S/128)
  attn<<<1024, 256, 0, stream>>>(QKb, VTb, OB);

  // out = o @ w_out^T : M=8192, N=2048, K=2048 ; 256x256 tiles, 256 blocks
  gemm_bt<2><<<256, 512, 0, stream>>>(OB, WOUTB, out, nullptr, 2048, 2048);
}

// Round 6
// 483.687 us; speedup vs baseline: 1.2839x; 1.0910x over previous
//
#include <hip/hip_runtime.h>

// ---------------------------------------------------------------------------
// SlidingWindowSelfAttention on MI355X (gfx950), bf16 MFMA pipeline:
//   cast(x,wqkv,wout) -> GEMM1 qkv (Q scaled, V written transposed)
//   -> flash attention (S^T = K Q^T formulation) -> GEMM2 out (fp32)
// R9 = R8 (128B-granule staging) with defensive sync structure:
//   - tile-top sync is __syncthreads() (compiler-modeled vmcnt0+lgkm0+bar;
//     removes the asm-barrier code-motion hazard, rule #18 class)
//   - stages issue at ph1 top (max DMA lead ~1 full tile of MFMA)
// Theory (R8, retest): R5b/R6/R7 all ~246us, MfmaUtil 36%, staging rate
//   10.6 B/cy/CU vs m201's proven 18.6 on identical tile/read volume.
//   Difference = global_load_lds source granularity: 128B-contiguous rows
//   (m201) vs our 64B frag rows. 128B L2 lines -> 64B sectors waste half
//   the fabric BW (10.6 = 18.6/2). Stage unit = 8 rows x 128B per gl16
//   with XOR chunk swizzle c^(row&7) on pre-swizzled global source (LDS
//   dest lane-linear, rule #21) and on ds_read address (involution).
//   Ring = 8 x 16KB quarters, stage 1 tile ahead, 2-phase K-tile loop.
// attn unchanged from R7 (passed): K dbuf + late V re-stage, counted vmcnt.
// ---------------------------------------------------------------------------

typedef __bf16 bf16x8 __attribute__((ext_vector_type(8)));
typedef float  f32x4  __attribute__((ext_vector_type(4)));
typedef unsigned short u16x4 __attribute__((ext_vector_type(4)));

#define MFMA(a, b, c) __builtin_amdgcn_mfma_f32_16x16x32_bf16(a, b, c, 0, 0, 0)

__device__ __forceinline__ unsigned short f2bf(float f) {
  union { float f; unsigned u; } v; v.f = f;
  unsigned r = v.u + 0x7FFFu + ((v.u >> 16) & 1u);   // RNE
  return (unsigned short)(r >> 16);
}

// async global->LDS, 16B/lane; LDS dest = wave-uniform base + lane*16
__device__ __forceinline__ void gl16(const void* g, void* l) {
  __builtin_amdgcn_global_load_lds(
      (const __attribute__((address_space(1))) unsigned int*)g,
      (__attribute__((address_space(3))) unsigned int*)l, 16, 0, 0);
}

// ---------------------------------------------------------------------------
__global__ void cast_bf16(const float4* __restrict__ in,
                          u16x4* __restrict__ out, int n4) {
  int i = blockIdx.x * blockDim.x + threadIdx.x;
  if (i < n4) {
    float4 v = in[i];
    u16x4 o;
    o[0] = f2bf(v.x); o[1] = f2bf(v.y); o[2] = f2bf(v.z); o[3] = f2bf(v.w);
    out[i] = o;
  }
}

// ---------------------------------------------------------------------------
// C = A * B^T. A:[M,K] bf16 row-major, B:[N,K] bf16 row-major (torch weight).
// 256x256 tile, BK=64, 8 waves each 128x64.
// LDS ring: 8 slots x 16KB. Quarter q (q = 4*tile + part): part 0,1 = A rows
// part*128..+127; part 2,3 = B rows (part-2)*128..+127. Slot = q&7 (tile
// parity picks ring half; halves are disjoint -> stage overlaps reads).
// Stage unit = 8 rows x 128B (1KB, one gl16): lane (r=lane>>3, c=lane&7)
// loads global [base+r][16B-chunk (c^r)] -> LDS linear lane*16. So
// LDS[u][r][c'] = G[row][c'^r]; ds_read uses chunk (m ^ (row&7)) for chunk
// m. Row r of a 128-row quarter lives at byte (r>>3)*1024 + (r&7)*128.
// 8-lane groups hit 8 distinct 4-bank groups -> conflict-free b128.
// Tile loop: __syncthreads() at top (drains tile g's DMA, certifies tile
// g-1 reads complete so ph1's stages may overwrite its slots); then
//   ph1: stage tile g+1 (4 quarters); ds_read kk=0; lgkm0+schedbar; 32 MFMA
//   ph2: ds_read kk=1; lgkm0+schedbar; 32 MFMA
// MODE 1: qkv epilogue (Q scaled 1/sqrt(D), V transposed into VT[B,H,D,S]).
// MODE 2: fp32 row-major C.
template <int MODE>
__global__ __launch_bounds__(512, 2) void gemm_bt(
    const unsigned short* __restrict__ A, const unsigned short* __restrict__ Bw,
    void* __restrict__ C1, void* __restrict__ C2, int K, int Nstride) {
  __shared__ __align__(16) unsigned char sm[131072];  // 8 x 16KB quarter ring
  const int tid = threadIdx.x, lane = tid & 63, w = tid >> 6;   // 8 waves
  const int l15 = lane & 15, lg = lane >> 4;
  const int wr = w >> 2, wc = w & 3;          // wave tile: rows wr*128, cols wc*64

  // staging lane constants: 8 rows x 128B unit, source chunk pre-swizzled
  const int rr = lane >> 3;                   // row within unit (0..7)
  const int cs = (((lane & 7) ^ rr) << 3);    // swizzled src chunk (shorts)

  // ds_read lane constants: frag row l15, K-chunk m = kk*4+lg stored at
  // chunk (m ^ (l15&7)); row l15 at byte (l15>>3)*1024 + (l15&7)*128.
  const int r7 = l15 & 7;
  const int mc0 = (l15 >> 3) * 1024 + r7 * 128 + ((lg ^ r7) << 4);
  const int mc1 = (l15 >> 3) * 1024 + r7 * 128 + (((4 + lg) ^ r7) << 4);

  // XCD-bijective swizzle (gridDim.x % 8 == 0 for both GEMMs), M=8192 fixed.
  int id = (int)blockIdx.x;
  int cpx = (int)gridDim.x >> 3;
  int sid = (id & 7) * cpx + (id >> 3);
  const int bm = (sid & 31) * 256;            // nmt = 8192/256 = 32
  const int bn = (sid >> 5) * 256;

  f32x4 acc[8][4] = {};
  const int nt = K >> 6;                      // K-tiles of 64

  auto stageQ = [&](int q) {                  // one 16KB quarter = 2 gl16/wave
    int qc = (q < 4 * nt) ? q : (4 * (nt - 1) + (q & 3));  // clamp tail (dummy)
    int t = qc >> 2, part = qc & 3;
    int kt = t << 6;
    unsigned char* dst = sm + (q & 7) * 16384 + w * 2048;
    const unsigned short* src =
        (part < 2)
            ? A  + (size_t)(bm + part * 128 + w * 16 + rr) * K + kt + cs
            : Bw + (size_t)(bn + (part - 2) * 128 + w * 16 + rr) * K + kt + cs;
    gl16(src, dst);                           // rows w*16  .. +7
    gl16(src + (size_t)8 * K, dst + 1024);    // rows w*16+8.. +15
  };

  // prologue: tile 0 staged (first loop-top __syncthreads certifies it)
  stageQ(0); stageQ(1); stageQ(2); stageQ(3);

  for (int g = 0; g < nt; ++g) {
    // drains tile g's DMA (vmcnt0) + certifies tile g-1 reads done (lgkm0+bar)
    __syncthreads();

    // stage tile g+1 into the opposite ring half (disjoint from tile g slots)
    stageQ((g << 2) + 4); stageQ((g << 2) + 5);
    stageQ((g << 2) + 6); stageQ((g << 2) + 7);

    const unsigned char* Abase = sm + ((((g << 2) + wr) & 7) << 14);
    const unsigned char* Bbase =
        sm + ((((g << 2) + 2 + (wc >> 1)) & 7) << 14) + ((wc & 1) << 13);
    bf16x8 af[8], bfr[4];

    // ---- ph1: kk=0 reads + MFMA ----
#pragma unroll
    for (int i = 0; i < 8; i++)
      af[i] = *(const bf16x8*)(Abase + i * 2048 + mc0);
#pragma unroll
    for (int j = 0; j < 4; j++)
      bfr[j] = *(const bf16x8*)(Bbase + j * 2048 + mc0);
    asm volatile("s_waitcnt lgkmcnt(0)" ::: "memory");
    __builtin_amdgcn_sched_barrier(0);
    __builtin_amdgcn_s_setprio(1);
#pragma unroll
    for (int i = 0; i < 8; i++)
#pragma unroll
      for (int j = 0; j < 4; j++)
        acc[i][j] = MFMA(af[i], bfr[j], acc[i][j]);
    __builtin_amdgcn_s_setprio(0);

    // ---- ph2: kk=1 reads + MFMA (overlaps ph1 MFMA execution) ----
#pragma unroll
    for (int i = 0; i < 8; i++)
      af[i] = *(const bf16x8*)(Abase + i * 2048 + mc1);
#pragma unroll
    for (int j = 0; j < 4; j++)
      bfr[j] = *(const bf16x8*)(Bbase + j * 2048 + mc1);
    asm volatile("s_waitcnt lgkmcnt(0)" ::: "memory");
    __builtin_amdgcn_sched_barrier(0);
    __builtin_amdgcn_s_setprio(1);
#pragma unroll
    for (int i = 0; i < 8; i++)
#pragma unroll
      for (int j = 0; j < 4; j++)
        acc[i][j] = MFMA(af[i], bfr[j], acc[i][j]);
    __builtin_amdgcn_s_setprio(0);
  }

  // drain dummy tail stages before exit: next block on this CU owns the LDS
  asm volatile("s_waitcnt vmcnt(0)" ::: "memory");

  // C/D layout: col n = lane&15, row m = (lane>>4)*4 + r  [m89/m91 verified]
  if (MODE == 1) {
    unsigned short* QK = (unsigned short*)C1;  // [8192][4096] = Q|K
    unsigned short* VT = (unsigned short*)C2;  // [2*16*128][4096]
    if (bn < 4096) {
      const float scl = (bn < 2048) ? 0.08838834764831845f : 1.0f;  // Q pre-scale
#pragma unroll
      for (int mi = 0; mi < 8; mi++) {
        int m0 = bm + wr * 128 + mi * 16 + lg * 4;
#pragma unroll
        for (int j = 0; j < 4; j++) {
          int n = bn + wc * 64 + j * 16 + l15;
#pragma unroll
          for (int r = 0; r < 4; r++)
            QK[(size_t)(m0 + r) * 4096 + n] = f2bf(acc[mi][j][r] * scl);
        }
      }
    } else {  // V: 4 consecutive m = consecutive s in VT -> packed 8B store
#pragma unroll
      for (int mi = 0; mi < 8; mi++) {
        int m0 = bm + wr * 128 + mi * 16 + lg * 4;
        int bb = m0 >> 12, s = m0 & 4095;
#pragma unroll
        for (int j = 0; j < 4; j++) {
          int n4 = bn + wc * 64 + j * 16 + l15 - 4096;
          int hh = n4 >> 7, d = n4 & 127;
          u16x4 pk;
#pragma unroll
          for (int r = 0; r < 4; r++) pk[r] = f2bf(acc[mi][j][r]);
          *(u16x4*)(VT + ((size_t)((bb * 16 + hh) * 128 + d) * 4096 + s)) = pk;
        }
      }
    }
  } else {
    float* C = (float*)C1;
#pragma unroll
    for (int mi = 0; mi < 8; mi++) {
      int m0 = bm + wr * 128 + mi * 16 + lg * 4;
#pragma unroll
      for (int j = 0; j < 4; j++) {
        int n = bn + wc * 64 + j * 16 + l15;
#pragma unroll
        for (int r = 0; r < 4; r++)
          C[(size_t)(m0 + r) * Nstride + n] = acc[mi][j][r];
      }
    }
  }
}

// ---------------------------------------------------------------------------
// Flash attention, S^T = K·Q^T formulation. Block = (b,h,128 queries),
// 4 waves x 32 queries. KV tiles of 64, span [q0-512, q0+128).
// R7 pipeline (unchanged, passed): K double-buffered, V re-staged in place,
// two counted vmcnt(4) per tile. LDS 66KB -> 2 blocks/CU.
__global__ __launch_bounds__(256, 2) void attn(
    const unsigned short* __restrict__ QK,  // [B*S][4096], Q pre-scaled
    const unsigned short* __restrict__ VT,  // [B*H*D][S]
    unsigned short* __restrict__ O) {       // [B*S][2048]
  __shared__ unsigned char sm[67584];
  // [0,16K): Kbuf0  [16K,32K): Kbuf1  [32K,48K): V frags [db8][kvs2][lane]
  // [48K,66K): P^T per wave 4608B: [m 32][kv 64] bf16, row stride 144B
  const int tid = threadIdx.x, lane = tid & 63, w = tid >> 6;
  const int l15 = lane & 15, lg = lane >> 4;
  const int bid = blockIdx.x;
  const int sid = (bid & 7) * 128 + (bid >> 3);   // XCD-contiguous q-chunks
  const int qc = sid & 31, h = (sid >> 5) & 15, b = sid >> 9;
  const int q0 = qc * 128;

  // Q fragments (B-operand: lane&15 = query, lg*8 = d-chunk) direct to regs
  bf16x8 qf[2][4];
#pragma unroll
  for (int mb = 0; mb < 2; mb++) {
    const unsigned short* qrow =
        QK + (size_t)(b * 4096 + q0 + (2 * w + mb) * 16 + l15) * 4096 + h * 128 + lg * 8;
#pragma unroll
    for (int ks = 0; ks < 4; ks++) qf[mb][ks] = *(const bf16x8*)(qrow + ks * 32);
  }

  float mrun[2] = {-1e30f, -1e30f}, lrun[2] = {0.f, 0.f};
  f32x4 oacc[8][2] = {};  // O^T tiles [db][mb]: row=d, col=query

  const int t0 = (q0 < 512) ? (512 - q0) >> 6 : 0;  // skip kv<0 tiles
  unsigned char* Ps = sm + 49152 + w * 4608;

  // prologue: stage K(t0)->Kbuf[t0&1] and V(t0)->V, full drain once
  {
    const int kv0 = q0 - 512 + t0 * 64;
#pragma unroll
    for (int u = 0; u < 4; u++) {
      int f = w + u * 4;
      int kvb = f >> 2, ks = f & 3;
      gl16(QK + (size_t)(b * 4096 + kv0 + kvb * 16 + l15) * 4096 + 2048 + h * 128 + ks * 32 + lg * 8,
           sm + (t0 & 1) * 16384 + f * 1024);
      int db = f >> 1, kvs = f & 1;
      gl16(VT + (size_t)((b * 16 + h) * 128 + db * 16 + l15) * 4096 + kv0 + kvs * 32 + lg * 8,
           sm + 32768 + f * 1024);
    }
  }
  asm volatile("s_waitcnt vmcnt(0)" ::: "memory");
  __builtin_amdgcn_s_barrier();

  for (int t = t0; t < 10; t++) {
    const int kv0 = q0 - 512 + t * 64;
    const int X = t & 1;
    const int tn = (t + 1 < 10) ? t + 1 : 9;        // clamp: dummy tail stage
    const int kvn = q0 - 512 + tn * 64;

    // stage K(t+1) -> Kbuf[X^1] (region's last readers synced 2 bars ago)
#pragma unroll
    for (int u = 0; u < 4; u++) {
      int f = w + u * 4;
      int kvb = f >> 2, ks = f & 3;
      gl16(QK + (size_t)(b * 4096 + kvn + kvb * 16 + l15) * 4096 + 2048 + h * 128 + ks * 32 + lg * 8,
           sm + (X ^ 1) * 16384 + f * 1024);
    }

    // S^T tiles [kvb][mb]: D row = kv (lg*4+r), D col = query (l15)
    f32x4 sacc[4][2] = {};
#pragma unroll
    for (int ks = 0; ks < 4; ks++)
#pragma unroll
      for (int kvb = 0; kvb < 4; kvb++) {
        bf16x8 kf = *(const bf16x8*)(sm + X * 16384 + (kvb * 4 + ks) * 1024 + lane * 16);
        sacc[kvb][0] = MFMA(kf, qf[0][ks], sacc[kvb][0]);
        sacc[kvb][1] = MFMA(kf, qf[1][ks], sacc[kvb][1]);
      }

    if (t <= 1 || t >= 8) {  // only window-edge / causal-edge tiles need masks
#pragma unroll
      for (int kvb = 0; kvb < 4; kvb++)
#pragma unroll
        for (int mb = 0; mb < 2; mb++) {
          int qg = q0 + w * 32 + mb * 16 + l15;
          int kgb = kv0 + kvb * 16 + lg * 4;
#pragma unroll
          for (int r = 0; r < 4; r++) {
            int diff = qg - (kgb + r);
            if (diff < 0 || diff > 512) sacc[kvb][mb][r] = -1e30f;
          }
        }
    }

#pragma unroll
    for (int mb = 0; mb < 2; mb++) {
      float tmax = -1e30f;
#pragma unroll
      for (int kvb = 0; kvb < 4; kvb++)
#pragma unroll
        for (int r = 0; r < 4; r++) tmax = fmaxf(tmax, sacc[kvb][mb][r]);
      tmax = fmaxf(tmax, __shfl_xor(tmax, 16));
      tmax = fmaxf(tmax, __shfl_xor(tmax, 32));
      float mnew = fmaxf(mrun[mb], tmax);
      float alpha = __expf(mrun[mb] - mnew);
      mrun[mb] = mnew;
      float lsum = 0.f;
#pragma unroll
      for (int kvb = 0; kvb < 4; kvb++) {
        u16x4 pk;
#pragma unroll
        for (int r = 0; r < 4; r++) {
          float p = __expf(sacc[kvb][mb][r] - mnew);
          lsum += p;
          pk[r] = f2bf(p);
        }
        *(u16x4*)(Ps + (mb * 16 + l15) * 144 + kvb * 32 + lg * 8) = pk;
      }
      lsum += __shfl_xor(lsum, 16);
      lsum += __shfl_xor(lsum, 32);
      lrun[mb] = lrun[mb] * alpha + lsum;
#pragma unroll
      for (int db = 0; db < 8; db++)
#pragma unroll
        for (int r = 0; r < 4; r++) oacc[db][mb][r] *= alpha;
    }

    // V(t) landed (FIFO: V(t) older than K(t+1); 8 -> 4 outstanding)
    asm volatile("s_waitcnt vmcnt(4)" ::: "memory");
    __builtin_amdgcn_s_barrier();

    // O^T += V^T · P^T  (A = V^T frag, lane-linear; B = P^T, contiguous b128)
#pragma unroll
    for (int kvs = 0; kvs < 2; kvs++) {
      bf16x8 pf0 = *(const bf16x8*)(Ps + (0 + l15) * 144 + kvs * 64 + lg * 16);
      bf16x8 pf1 = *(const bf16x8*)(Ps + (16 + l15) * 144 + kvs * 64 + lg * 16);
#pragma unroll
      for (int db = 0; db < 8; db++) {
        bf16x8 vf = *(const bf16x8*)(sm + 32768 + (db * 2 + kvs) * 1024 + lane * 16);
        oacc[db][0] = MFMA(vf, pf0, oacc[db][0]);
        oacc[db][1] = MFMA(vf, pf1, oacc[db][1]);
      }
    }
    __builtin_amdgcn_s_barrier();   // all PV reads of V done block-wide

    // stage V(t+1) -> V region
#pragma unroll
    for (int u = 0; u < 4; u++) {
      int f = w + u * 4;
      int db = f >> 1, kvs = f & 1;
      gl16(VT + (size_t)((b * 16 + h) * 128 + db * 16 + l15) * 4096 + kvn + kvs * 32 + lg * 8,
           sm + 32768 + f * 1024);
    }
    // K(t+1) landed (FIFO: K(t+1) older than V(t+1); 8 -> 4 outstanding)
    asm volatile("s_waitcnt vmcnt(4)" ::: "memory");
    __builtin_amdgcn_s_barrier();
  }

  // drain dummy tail stages before exit (next block owns this LDS)
  asm volatile("s_waitcnt vmcnt(0)" ::: "memory");

#pragma unroll
  for (int mb = 0; mb < 2; mb++) {
    float inv = 1.0f / lrun[mb];
    int s = q0 + w * 32 + mb * 16 + l15;
    unsigned short* orow = O + (size_t)(b * 4096 + s) * 2048 + h * 128 + lg * 4;
#pragma unroll
    for (int db = 0; db < 8; db++) {
      u16x4 pk;
#pragma unroll
      for (int r = 0; r < 4; r++) pk[r] = f2bf(oacc[db][mb][r] * inv);
      *(u16x4*)(orow + db * 16) = pk;
    }
  }
}

// ---------------------------------------------------------------------------
extern "C" void kernel_launch(void* const* d_in, const int* in_sizes, int n_in,
                              void* d_out, int out_size, void* d_ws, size_t ws_size,
                              hipStream_t stream) {
  const float* x = (const float*)d_in[0];       // [2,4096,2048]
  const float* w_qkv = (const float*)d_in[1];   // [6144,2048]
  const float* w_out = (const float*)d_in[2];   // [2048,2048]
  float* out = (float*)d_out;                   // [2,4096,2048] fp32

  char* ws = (char*)d_ws;
  unsigned short* XB    = (unsigned short*)(ws);                         // 32M
  unsigned short* WQKVB = (unsigned short*)(ws + 33554432);              // 24M
  unsigned short* WOUTB = (unsigned short*)(ws + 58720256);              // 8M
  unsigned short* QKb   = (unsigned short*)(ws + 67108864);              // 64M
  unsigned short* VTb   = (unsigned short*)(ws + 134217728);             // 32M
  unsigned short* OB    = XB;  // XB dead after GEMM1; reuse for attention output
  // total workspace: 160 MiB

  cast_bf16<<<16384, 256, 0, stream>>>((const float4*)x, (u16x4*)XB, 4194304);
  cast_bf16<<<12288, 256, 0, stream>>>((const float4*)w_qkv, (u16x4*)WQKVB, 3145728);
  cast_bf16<<<4096, 256, 0, stream>>>((const float4*)w_out, (u16x4*)WOUTB, 1048576);

  // qkv = x @ w_qkv^T : M=8192, N=6144, K=2048 ; 256x256 tiles, 768 blocks
  gemm_bt<1><<<768, 512, 0, stream>>>(XB, WQKVB, QKb, VTb, 2048, 0);

  // sliding-window attention: grid = B*H*(S/128)
  attn<<<1024, 256, 0, stream>>>(QKb, VTb, OB);

  // out = o @ w_out^T : M=8192, N=2048, K=2048 ; 256x256 tiles, 256 blocks
  gemm_bt<2><<<256, 512, 0, stream>>>(OB, WOUTB, out, nullptr, 2048, 2048);
}